// Round 15
// baseline (100.590 us; speedup 1.0000x reference)
//
#include <hip/hip_runtime.h>
#include <math.h>
#include <stdint.h>

// ---------------------------------------------------------------------------
// Algebraic reductions (verified through r14, absmax 4.88e-4 with 2-term):
//  * 2-step loop idempotent -> run once; node branch cancels entirely.
//  * Factored GEMM (rank-128): edge_f = x_edge @ et_w, g = edge_f @ wih^T.
//  * Fully fused: ef GEMM -> ef_s (LDS f32) -> g GEMM -> gates+pool.
//  * 2-term split: B single bf16; A hi/lo split. cvt_pk conversions (r14).
//  * Round-15: TLP. r12's 512-thread BM=128 geometry (the only config that
//    reached 40% occupancy) now spill-free: 2-term live set ~90 VGPR,
//    launch_bounds(512,2) caps at 256. 8 waves/block x 2 blocks/CU =
//    16 waves/CU (2x r14). Phase bodies = r14 (validated).
// ---------------------------------------------------------------------------

typedef __attribute__((ext_vector_type(8))) short short8;
typedef __attribute__((ext_vector_type(4))) float f32x4;

#define DEVINL __device__ __forceinline__

DEVINL float sigmoidf_(float x) { return 1.0f / (1.0f + __expf(-x)); }
DEVINL float tanhf_(float x) {
    float e = __expf(2.0f * x);
    return (e - 1.0f) / (e + 1.0f);
}
DEVINL short bf16_rne(float f) {
    uint32_t u = __float_as_uint(f);
    u += 0x7FFFu + ((u >> 16) & 1u);
    return (short)(u >> 16);
}
DEVINL float bf16_to_f(short s) {
    return __uint_as_float(((uint32_t)(uint16_t)s) << 16);
}
// HW-packed f32x8 -> bf16 hi + lo planes (1 cvt_pk per pair per plane).
DEVINL void cvt_hilo8(const float av[8], short8* h8, short8* l8) {
    union { uint32_t u[4]; short8 s; } H, L;
#pragma unroll
    for (int i = 0; i < 4; ++i) {
        float a0 = av[2 * i], a1 = av[2 * i + 1];
        uint32_t ph;
        asm("v_cvt_pk_bf16_f32 %0, %1, %2" : "=v"(ph) : "v"(a0), "v"(a1));
        float h0 = __uint_as_float(ph << 16);
        float h1 = __uint_as_float(ph & 0xFFFF0000u);
        uint32_t pl;
        asm("v_cvt_pk_bf16_f32 %0, %1, %2" : "=v"(pl) : "v"(a0 - h0), "v"(a1 - h1));
        H.u[i] = ph;
        L.u[i] = pl;
    }
    *h8 = H.s;
    *l8 = L.s;
}
DEVINL void gload_lds16(const void* g, void* l) {
    __builtin_amdgcn_global_load_lds(
        (const __attribute__((address_space(1))) void*)(uintptr_t)g,
        (__attribute__((address_space(3))) void*)(uint32_t)(uintptr_t)l,
        16, 0, 0);
}
// LDS-only barrier: does NOT drain vmcnt (in-flight global prefetch survives)
DEVINL void ldsbar() {
    asm volatile("s_waitcnt lgkmcnt(0)\n\ts_barrier" ::: "memory");
    __builtin_amdgcn_sched_barrier(0);
}

// ---------------- prep: weight fragment packing ----------------------------
// B-fragment convention (validated r3-r14): col n = ct*16+(l&15),
// k = kt*32 + ((l>>4)&3)*8 + j.
// bid <256   : et_w [512,128] -> Bf1 [kt16][ct8][lane][j]   (single bf16)
// bid 256-447: wih  [384,128] -> Bf2 [kt4][ct24][lane][j]   (single bf16)
// bid >=448  : heads W1 (3x[256,512]) -> Wf1_hi/lo [h][kt8][ct32][lane][j]
__global__ __launch_bounds__(256) void prep_all(
    const float* __restrict__ et_w, const float* __restrict__ wih,
    const float* __restrict__ w1a, const float* __restrict__ w1b,
    const float* __restrict__ w1c,
    short* __restrict__ Bf1, short* __restrict__ Bf2,
    short* __restrict__ Wf1_hi, short* __restrict__ Wf1_lo)
{
    const int bid = blockIdx.x, t = threadIdx.x;
    if (bid < 256) {
        int idx = bid * 256 + t;            // [0,65536)
        int k = idx >> 7, n = idx & 127;
        float v = et_w[(size_t)k * 128 + n];
        short hi = bf16_rne(v);
        int kt = k >> 5, ct = n >> 4;
        int lane = (((k >> 3) & 3) << 4) | (n & 15);
        int j = k & 7;
        size_t s0 = (((size_t)kt * 8 + ct) * 64 + lane) * 8 + j;
        Bf1[s0] = hi;
    } else if (bid < 448) {
        int idx = (bid - 256) * 256 + t;    // [0,49152)
        int n = idx >> 7, k = idx & 127;
        float v = wih[(size_t)n * 128 + k];
        short hi = bf16_rne(v);
        int kt = k >> 5, ct = n >> 4;
        int lane = (((k >> 3) & 3) << 4) | (n & 15);
        int j = k & 7;
        size_t s0 = (((size_t)kt * 24 + ct) * 64 + lane) * 8 + j;
        Bf2[s0] = hi;
    } else {
        int idx = (bid - 448) * 256 + t;    // [0,393216)
        int h = idx >> 17;
        int r = idx & 131071;
        int k = r >> 9, c = r & 511;
        const float* w1 = (h == 0) ? w1a : (h == 1) ? w1b : w1c;
        float v = w1[(size_t)k * 512 + c];
        short hi = bf16_rne(v), lo = bf16_rne(v - bf16_to_f(hi));
        int kt = k >> 5, ct = c >> 4;
        int lane = (((k >> 3) & 3) << 4) | (c & 15);
        int j = k & 7;
        size_t fidx = ((((size_t)h * 8 + kt) * 32 + ct) * 64 + lane) * 8 + j;
        Wf1_hi[fidx] = hi;
        Wf1_lo[fidx] = lo;
    }
}

// one phase-1 iteration (2-term, cvt_pk; BM=128, 8 waves).
// A frag reads use grt = rq*4+rt; A planes 8KB apart within each buffer.
#define PH1_ITER(KT, BH0, BH1, NBH0, NBH1,                                    \
                 PCV0, PCV1, PLD0, PLD1, RBUF, WBUF)                          \
    {                                                                         \
        if ((KT) < 15) {                                                      \
            const short* bkt = Bf1 + (size_t)((KT) + 1) * 4096;               \
            NBH0 = *(const short8*)(bkt + ct0 * 512 + ln8);                   \
            NBH1 = *(const short8*)(bkt + ct1 * 512 + ln8);                   \
            float av[8] = {PCV0.x, PCV0.y, PCV0.z, PCV0.w,                    \
                           PCV1.x, PCV1.y, PCV1.z, PCV1.w};                   \
            short8 h8, l8;                                                    \
            cvt_hilo8(av, &h8, &l8);                                          \
            *(short8*)(smem + (WBUF) + aslotb) = h8;                          \
            *(short8*)(smem + (WBUF) + 8192 + aslotb) = l8;                   \
        }                                                                     \
        if ((KT) < 14) {                                                      \
            PLD0 = *(const float4*)(aptr + (size_t)((KT) + 2) * 32);          \
            PLD1 = *(const float4*)(aptr + (size_t)((KT) + 2) * 32 + 4);      \
        }                                                                     \
        {                                                                     \
            const char* Ah_c = smem + (RBUF);                                 \
            short8 Ahf[4], Alf[4];                                            \
            _Pragma("unroll") for (int rt = 0; rt < 4; ++rt) {                \
                int grt = rq * 4 + rt;                                        \
                Ahf[rt] = *(const short8*)(Ah_c + (grt * 64 + lane) * 16);    \
                Alf[rt] = *(const short8*)(Ah_c + 8192 + (grt * 64 + lane) * 16); \
            }                                                                 \
            _Pragma("unroll") for (int rt = 0; rt < 4; ++rt) {                \
                acc1[rt][0] = __builtin_amdgcn_mfma_f32_16x16x32_bf16(Ahf[rt], BH0, acc1[rt][0], 0, 0, 0); \
                acc1[rt][0] = __builtin_amdgcn_mfma_f32_16x16x32_bf16(Alf[rt], BH0, acc1[rt][0], 0, 0, 0); \
                acc1[rt][1] = __builtin_amdgcn_mfma_f32_16x16x32_bf16(Ahf[rt], BH1, acc1[rt][1], 0, 0, 0); \
                acc1[rt][1] = __builtin_amdgcn_mfma_f32_16x16x32_bf16(Alf[rt], BH1, acc1[rt][1], 0, 0, 0); \
            }                                                                 \
        }                                                                     \
        ldsbar();                                                             \
    }

// ---------------- fused: BM=128, 512 thr, 8 waves, 2 blocks/CU -------------
// Block = 2 (b,i) groups. Waves: rq = wv>>2 (64-row half), cq = wv&3.
// LDS map (70656 B):
//  phase1: A dbuf 2*16KB @0..32768 (hi 8KB + lo 8KB per buf; B in regs)
//  phase2: ef_s [128][132] f32 @0..67584 (overlay)
//  phase3: per-team two-pass acc[2][6]; A from ef_s (cvt_pk), B in regs
//          (6 short8), gates fused per pass
//  epilogue: dual-team pool; scratch @67584 (2 x 1536 B)
__global__ __launch_bounds__(512, 2) void fused_kernel(
    const float* __restrict__ x_edge,
    const short* __restrict__ Bf1, const short* __restrict__ Bf2,
    const float* __restrict__ et_b,
    const float* __restrict__ bih, const float* __restrict__ bhh,
    const float* __restrict__ natt_w, const float* __restrict__ eatt_w,
    float* __restrict__ nh_p, float* __restrict__ u_out)
{
    __shared__ __align__(16) char smem[70656];
    const int t = threadIdx.x;
    const int wv = t >> 6, lane = t & 63;
    const int cq = wv & 3, rq = wv >> 2;
    const int g2 = blockIdx.x;
    const size_t bm = (size_t)g2 * 128;

    const int arow = t >> 2, akb = t & 3;
    const int aslotb = (((arow >> 4) * 64) + ((akb << 4) | (arow & 15))) * 16;
    const float* aptr = x_edge + (bm + arow) * 512 + akb * 8;

    const int ct0 = cq * 2, ct1 = cq * 2 + 1;
    const int ln8 = lane * 8;

    f32x4 acc1[4][2] = {};

    // phase-1 registers: A 2-deep (slotA = even kt, slotB = odd kt), B dbuf
    float4 paA0, paA1, paB0, paB1;
    short8 bhA0, bhA1, bhB0, bhB1;

    // ---- prologue: A(0),A(1) -> regs; B(0) -> regs; A(0) -> LDS buf0 ----
    paA0 = *(const float4*)(aptr);
    paA1 = *(const float4*)(aptr + 4);
    paB0 = *(const float4*)(aptr + 32);
    paB1 = *(const float4*)(aptr + 36);
    {
        const short* bkt = Bf1;
        bhA0 = *(const short8*)(bkt + ct0 * 512 + ln8);
        bhA1 = *(const short8*)(bkt + ct1 * 512 + ln8);
    }
    {
        float av[8] = {paA0.x, paA0.y, paA0.z, paA0.w,
                       paA1.x, paA1.y, paA1.z, paA1.w};
        short8 h8, l8;
        cvt_hilo8(av, &h8, &l8);
        *(short8*)(smem + aslotb) = h8;
        *(short8*)(smem + 8192 + aslotb) = l8;
    }
    ldsbar();

    // ---- phase 1: 16 kt, lgkm-only barrier, global prefetch in flight ----
    for (int kt = 0; kt < 16; kt += 2) {
        PH1_ITER(kt, bhA0, bhA1, bhB0, bhB1,
                 paB0, paB1, paA0, paA1, 0, 16384)
        PH1_ITER(kt + 1, bhB0, bhB1, bhA0, bhA1,
                 paA0, paA1, paB0, paB1, 16384, 0)
    }
    __syncthreads();

    // ---- phase 2: acc1 + et_b -> ef_s [128][132] f32 @0 ----
    float* ef_s = (float*)smem;
#pragma unroll
    for (int c = 0; c < 2; ++c) {
        int col = cq * 32 + c * 16 + (lane & 15);
        float bias = et_b[col];
#pragma unroll
        for (int rt = 0; rt < 4; ++rt) {
#pragma unroll
            for (int q = 0; q < 4; ++q) {
                int row = rq * 64 + rt * 16 + ((lane >> 4) << 2) + q;
                ef_s[row * 132 + col] = acc1[rt][c][q] + bias;
            }
        }
    }
    __syncthreads();

    // ---- phase 3 + gates: per team (rq), two rt-pair passes, acc[2][6] ----
    const int EHP = 132;
    float* ef_t = (float*)smem + rq * (64 * EHP);   // team's 64-row half
#pragma unroll
    for (int rtp = 0; rtp < 2; ++rtp) {
        f32x4 acch[2][6] = {};
#pragma unroll
        for (int kt = 0; kt < 4; ++kt) {
            const short* bkt = Bf2 + (size_t)kt * 12288;
            short8 Ah[2], Al[2];
#pragma unroll
            for (int r = 0; r < 2; ++r) {
                int rt = rtp * 2 + r;
                const float* src = ef_t + (rt * 16 + (lane & 15)) * 132
                                 + kt * 32 + (lane >> 4) * 8;
                float4 v0 = *(const float4*)(src);
                float4 v1 = *(const float4*)(src + 4);
                float av[8] = {v0.x, v0.y, v0.z, v0.w, v1.x, v1.y, v1.z, v1.w};
                cvt_hilo8(av, &Ah[r], &Al[r]);
            }
#pragma unroll
            for (int c = 0; c < 6; ++c) {
                int ctg = ((c >> 1) << 3) + (cq << 1) + (c & 1);
                short8 Bh = *(const short8*)(bkt + ctg * 512 + ln8);
#pragma unroll
                for (int r = 0; r < 2; ++r) {
                    acch[r][c] = __builtin_amdgcn_mfma_f32_16x16x32_bf16(Ah[r], Bh, acch[r][c], 0, 0, 0);
                    acch[r][c] = __builtin_amdgcn_mfma_f32_16x16x32_bf16(Al[r], Bh, acch[r][c], 0, 0, 0);
                }
            }
        }
        __syncthreads();    // all waves done reading this pass's ef_s rows
        // gates for team rows rtp*32..+31 (overwrite same rows in-place)
#pragma unroll
        for (int cc = 0; cc < 2; ++cc) {
            int o = (cq << 5) + (cc << 4) + (lane & 15);
            float bco = bih[o] + bhh[o];
            float bcz = bih[128 + o] + bhh[128 + o];
            float bcn = bih[256 + o];
            float bn3 = bhh[256 + o];
#pragma unroll
            for (int r = 0; r < 2; ++r) {
#pragma unroll
                for (int q = 0; q < 4; ++q) {
                    int row = rtp * 32 + r * 16 + ((lane >> 4) << 2) + q;
                    float rr = sigmoidf_(acch[r][cc][q] + bco);
                    float zz = sigmoidf_(acch[r][2 + cc][q] + bcz);
                    float nn = tanhf_(acch[r][4 + cc][q] + bcn + rr * bn3);
                    ef_t[row * EHP + o] = (1.0f - zz) * nn;
                }
            }
        }
    }
    __syncthreads();

    // ---- epilogue: dual-team softmax-pool (validated r5/r12) ----
    const int tt = cq * 64 + lane;              // team-local 0..255
    const int G = g2 * 2 + rq;                  // global group id
    float* eh_g = ef_t;
    float* red  = (float*)(smem + 67584 + rq * 1536);
    float* s2v  = red + 256;
    float* ewv  = s2v + 64;
    {
        int j = tt >> 2, q = tt & 3;
        const float* row = eh_g + j * EHP + q * 32;
        const float* wb = natt_w + 128 + q * 32;
        float a = 0.f;
#pragma unroll
        for (int k2 = 0; k2 < 32; ++k2) a = fmaf(row[k2], wb[k2], a);
        red[tt] = a;
    }
    __syncthreads();
    if (tt < 64) s2v[tt] = red[4 * tt] + red[4 * tt + 1] + red[4 * tt + 2] + red[4 * tt + 3];
    __syncthreads();
    if (tt < 64) {
        float m = -1e30f;
        for (int j = 0; j < 64; ++j) m = fmaxf(m, s2v[j]);
        ewv[tt] = __expf(s2v[tt] - m);
    }
    __syncthreads();
    float inv = 0.f;
    for (int j = 0; j < 64; ++j) inv += ewv[j];
    inv = 1.0f / inv;
    {
        int o = tt & 127, h = tt >> 7;
        float a = 0.f;
        for (int j = h * 32; j < h * 32 + 32; ++j)
            a = fmaf(ewv[j], eh_g[j * EHP + o], a);
        __syncthreads();
        red[tt] = a;
    }
    __syncthreads();
    if (tt < 128) {
        float v = (red[tt] + red[tt + 128]) * inv;
        nh_p[(size_t)G * 128 + tt] = v;
        red[tt] = v * eatt_w[tt];
    }
    __syncthreads();
    for (int s = 64; s > 0; s >>= 1) {
        if (tt < s) red[tt] += red[tt + s];
        __syncthreads();
    }
    if (tt == 0) u_out[G] = red[0];
}

// -------- classifier input --------------------------------------------------
__global__ __launch_bounds__(128) void ci_kernel(
    const float* __restrict__ nh_p, const float* __restrict__ u,
    const int* __restrict__ pairs, float* __restrict__ ci)
{
    const int bp = blockIdx.x;
    const int b  = bp >> 7;
    const int t  = threadIdx.x;
    int i0 = pairs[bp * 2 + 0];
    int i1 = pairs[bp * 2 + 1];
    const float* n0 = nh_p + (size_t)(b * 64 + i0) * 128;
    const float* n1 = nh_p + (size_t)(b * 64 + i1) * 128;
    float s = sigmoidf_(u[b * 64 + i1] - u[b * 64 + i0]);
    float v0 = n0[t], v1 = n1[t];
    ci[(size_t)bp * 256 + t]       = 0.5f * (v0 + v1);
    ci[(size_t)bp * 256 + 128 + t] = s * v1 + (1.0f - s) * v0;
}

// -------- fused head: layer1 MFMA GEMM + ReLU + layer2 (w2 in LDS) ---------
__global__ __launch_bounds__(256, 1) void headcls_kernel(
    const float* __restrict__ ci,
    const short* __restrict__ Wf1_hi, const short* __restrict__ Wf1_lo,
    const float* __restrict__ b1a, const float* __restrict__ b1b,
    const float* __restrict__ b1c,
    const float* __restrict__ w2a, const float* __restrict__ w2b,
    const float* __restrict__ w2c,
    const float* __restrict__ b2a, const float* __restrict__ b2b,
    const float* __restrict__ b2c,
    float* __restrict__ out)
{
    __shared__ __align__(16) char smem[139264];
    const int t = threadIdx.x;
    const int wv = t >> 6, lane = t & 63;
    const int rb = blockIdx.x;
    const int hd = blockIdx.y;
    const float* b1 = hd == 0 ? b1a : hd == 1 ? b1b : b1c;
    const float* w2 = hd == 0 ? w2a : hd == 1 ? w2b : w2c;
    const float* b2 = hd == 0 ? b2a : hd == 1 ? b2b : b2c;
    const int od  = hd == 0 ? 6 : hd == 1 ? 5 : 3;
    const int off = hd == 0 ? 0 : hd == 1 ? 6 : 11;

    const int arow = t >> 2, akb = t & 3;
    const int abyte = ((((arow >> 4) * 64) + ((akb << 4) | (arow & 15))) * 8) * 2;
    const float* aptr = ci + ((size_t)rb * 32 + arow) * 256 + akb * 8;

    f32x4 acc[2][8] = {};

    float4 a0, a1;
    if (t < 128) {
        a0 = *(const float4*)(aptr);
        a1 = *(const float4*)(aptr + 4);
    }
    {
        const char* sh = (const char*)(Wf1_hi + (size_t)hd * 8 * 32 * 512);
        const char* sl = (const char*)(Wf1_lo + (size_t)hd * 8 * 32 * 512);
#pragma unroll
        for (int i = 0; i < 8; ++i) {
            int ch = i * 4 + wv;
            int o2 = ch * 1024 + lane * 16;
            gload_lds16(sh + o2, smem + ch * 1024);
            gload_lds16(sl + o2, smem + 32768 + ch * 1024);
        }
    }
    if (t < 128) {
        float av[8] = {a0.x, a0.y, a0.z, a0.w, a1.x, a1.y, a1.z, a1.w};
        short8 h8, l8;
        cvt_hilo8(av, &h8, &l8);
        *(short8*)(smem + 131072 + abyte) = h8;
        *(short8*)(smem + 131072 + 2048 + abyte) = l8;
    }
    __syncthreads();

    for (int kt = 0; kt < 8; ++kt) {
        const int cur = kt & 1;
        const char* Bh_c = smem + cur * 65536;
        const char* Bl_c = Bh_c + 32768;
        const char* Ah_c = smem + 131072 + cur * 4096;
        const char* Al_c = Ah_c + 2048;

        float4 b0, b1v;
        if (kt < 7) {
            const char* sh = (const char*)(Wf1_hi + ((size_t)hd * 8 + kt + 1) * 32 * 512);
            const char* sl = (const char*)(Wf1_lo + ((size_t)hd * 8 + kt + 1) * 32 * 512);
            char* dBh = smem + (cur ^ 1) * 65536;
#pragma unroll
            for (int i = 0; i < 8; ++i) {
                int ch = i * 4 + wv;
                int o2 = ch * 1024 + lane * 16;
                gload_lds16(sh + o2, dBh + ch * 1024);
                gload_lds16(sl + o2, dBh + 32768 + ch * 1024);
            }
            if (t < 128) {
                b0  = *(const float4*)(aptr + (size_t)(kt + 1) * 32);
                b1v = *(const float4*)(aptr + (size_t)(kt + 1) * 32 + 4);
            }
        }

        short8 Ah[2], Al[2];
#pragma unroll
        for (int rt = 0; rt < 2; ++rt) {
            Ah[rt] = *(const short8*)(Ah_c + (rt * 64 + lane) * 16);
            Al[rt] = *(const short8*)(Al_c + (rt * 64 + lane) * 16);
        }
#pragma unroll
        for (int c = 0; c < 8; ++c) {
            int ctg = wv * 8 + c;
            short8 Bh = *(const short8*)(Bh_c + (ctg * 64 + lane) * 16);
            short8 Bl = *(const short8*)(Bl_c + (ctg * 64 + lane) * 16);
#pragma unroll
            for (int rt = 0; rt < 2; ++rt) {
                acc[rt][c] = __builtin_amdgcn_mfma_f32_16x16x32_bf16(Ah[rt], Bh, acc[rt][c], 0, 0, 0);
                acc[rt][c] = __builtin_amdgcn_mfma_f32_16x16x32_bf16(Al[rt], Bh, acc[rt][c], 0, 0, 0);
                acc[rt][c] = __builtin_amdgcn_mfma_f32_16x16x32_bf16(Ah[rt], Bl, acc[rt][c], 0, 0, 0);
            }
        }

        if (kt < 7 && t < 128) {
            float av[8] = {b0.x, b0.y, b0.z, b0.w, b1v.x, b1v.y, b1v.z, b1v.w};
            short8 h8, l8;
            cvt_hilo8(av, &h8, &l8);
            char* dAh = smem + 131072 + (cur ^ 1) * 4096;
            *(short8*)(dAh + abyte) = h8;
            *(short8*)(dAh + 2048 + abyte) = l8;
        }
        __syncthreads();
    }

    // h_s [32][516] @0 ; w2_s @66048 (both overlay B bufs, post-sync)
    float* h_s  = (float*)smem;
    float* w2_s = (float*)(smem + 66048);
    for (int idx = t; idx < 512 * od; idx += 256) w2_s[idx] = w2[idx];
#pragma unroll
    for (int c = 0; c < 8; ++c) {
        int ctg = wv * 8 + c;
        int col = ctg * 16 + (lane & 15);
        float bias = b1[col];
#pragma unroll
        for (int rt = 0; rt < 2; ++rt) {
#pragma unroll
            for (int q = 0; q < 4; ++q) {
                int row = rt * 16 + ((lane >> 4) << 2) + q;
                h_s[row * 516 + col] = fmaxf(acc[rt][c][q] + bias, 0.f);
            }
        }
    }
    __syncthreads();

    {
        int row = t >> 3, o = t & 7;
        if (o < od) {
            const float* hr = h_s + row * 516;
            float a = b2[o];
            for (int c = 0; c < 512; ++c)
                a = fmaf(hr[c], w2_s[c * od + o], a);
            out[((size_t)rb * 32 + row) * 14 + off + o] = a;
        }
    }
}

// ---------------------------------------------------------------------------
extern "C" void kernel_launch(void* const* d_in, const int* in_sizes, int n_in,
                              void* d_out, int out_size, void* d_ws, size_t ws_size,
                              hipStream_t stream)
{
    const float* x_edge   = (const float*)d_in[1];
    const float* et_w     = (const float*)d_in[6];
    const float* et_b     = (const float*)d_in[7];
    const float* egru_wih = (const float*)d_in[11];
    const float* egru_bih = (const float*)d_in[12];
    const float* egru_bhh = (const float*)d_in[13];
    const float* natt_w   = (const float*)d_in[14];
    const float* eatt_w   = (const float*)d_in[16];
    const float* lr_w1 = (const float*)d_in[18];
    const float* lr_b1 = (const float*)d_in[19];
    const float* lr_w2 = (const float*)d_in[20];
    const float* lr_b2 = (const float*)d_in[21];
    const float* cr_w1 = (const float*)d_in[22];
    const float* cr_b1 = (const float*)d_in[23];
    const float* cr_w2 = (const float*)d_in[24];
    const float* cr_b2 = (const float*)d_in[25];
    const float* mr_w1 = (const float*)d_in[26];
    const float* mr_b1 = (const float*)d_in[27];
    const float* mr_w2 = (const float*)d_in[28];
    const float* mr_b2 = (const float*)d_in[29];
    const int* pairs   = (const int*)d_in[30];
    float* out = (float*)d_out;
    char* ws = (char*)d_ws;

    // workspace layout (bytes) — 4.43 MB total
    short* Bf1    = (short*)(ws + 0);          // 131072 (single plane)
    short* Bf2    = (short*)(ws + 131072);     // 98304  (single plane)
    short* Wf1_hi = (short*)(ws + 229376);     // 786432
    short* Wf1_lo = (short*)(ws + 1015808);    // 786432
    float* nh_p   = (float*)(ws + 1802240);    // 524288
    float* u      = (float*)(ws + 2326528);    // 4096
    float* ci     = (float*)(ws + 2330624);    // 2097152 -> end 4427776

    prep_all<<<1984, 256, 0, stream>>>(et_w, egru_wih, lr_w1, cr_w1, mr_w1,
                                       Bf1, Bf2, Wf1_hi, Wf1_lo);

    fused_kernel<<<512, 512, 0, stream>>>(
        x_edge, Bf1, Bf2, et_b, egru_bih, egru_bhh, natt_w, eatt_w, nh_p, u);

    ci_kernel<<<2048, 128, 0, stream>>>(nh_p, u, pairs, ci);

    headcls_kernel<<<dim3(64, 3), 256, 0, stream>>>(
        ci, Wf1_hi, Wf1_lo, lr_b1, cr_b1, mr_b1,
        lr_w2, cr_w2, mr_w2, lr_b2, cr_b2, mr_b2, out);
}

// Round 16
// 80.940 us; speedup vs baseline: 1.2428x; 1.2428x over previous
//
#include <hip/hip_runtime.h>
#include <math.h>
#include <stdint.h>

// ---------------------------------------------------------------------------
// Algebraic reductions (verified through r14, absmax 4.88e-4 with 2-term):
//  * 2-step loop idempotent -> run once; node branch cancels entirely.
//  * Factored GEMM (rank-128): edge_f = x_edge @ et_w, g = edge_f @ wih^T.
//  * Fully fused: ef GEMM -> ef_s (LDS f32) -> g GEMM -> gates+pool.
//  * 2-term split: B single bf16; A hi/lo split. cvt_pk conversions (r14).
//  * Round-16: r14 base (best, 256thr/4waves) + two targeted fixes:
//      - phase 1 processes 2 kt per barrier (4 A buffers: 2 step-bufs x 2 kt,
//        read cur / write nxt) -> 8 barriers instead of 16. Same per-element
//        MFMA order (bit-identical). LDS unchanged at 35328 B.
//      - pool max/sum via __shfl_xor butterflies (removes 2x64 serial LDS
//        reads per thread; deterministic, wave-identical).
//    (r12/r15 established 512-thr blocks regress; r10/r12 spills reverted.)
// ---------------------------------------------------------------------------

typedef __attribute__((ext_vector_type(8))) short short8;
typedef __attribute__((ext_vector_type(4))) float f32x4;

#define DEVINL __device__ __forceinline__

DEVINL float sigmoidf_(float x) { return 1.0f / (1.0f + __expf(-x)); }
DEVINL float tanhf_(float x) {
    float e = __expf(2.0f * x);
    return (e - 1.0f) / (e + 1.0f);
}
DEVINL short bf16_rne(float f) {
    uint32_t u = __float_as_uint(f);
    u += 0x7FFFu + ((u >> 16) & 1u);
    return (short)(u >> 16);
}
DEVINL float bf16_to_f(short s) {
    return __uint_as_float(((uint32_t)(uint16_t)s) << 16);
}
// HW-packed f32x8 -> bf16 hi + lo planes (1 cvt_pk per pair per plane).
DEVINL void cvt_hilo8(const float av[8], short8* h8, short8* l8) {
    union { uint32_t u[4]; short8 s; } H, L;
#pragma unroll
    for (int i = 0; i < 4; ++i) {
        float a0 = av[2 * i], a1 = av[2 * i + 1];
        uint32_t ph;
        asm("v_cvt_pk_bf16_f32 %0, %1, %2" : "=v"(ph) : "v"(a0), "v"(a1));
        float h0 = __uint_as_float(ph << 16);
        float h1 = __uint_as_float(ph & 0xFFFF0000u);
        uint32_t pl;
        asm("v_cvt_pk_bf16_f32 %0, %1, %2" : "=v"(pl) : "v"(a0 - h0), "v"(a1 - h1));
        H.u[i] = ph;
        L.u[i] = pl;
    }
    *h8 = H.s;
    *l8 = L.s;
}
DEVINL void gload_lds16(const void* g, void* l) {
    __builtin_amdgcn_global_load_lds(
        (const __attribute__((address_space(1))) void*)(uintptr_t)g,
        (__attribute__((address_space(3))) void*)(uint32_t)(uintptr_t)l,
        16, 0, 0);
}
// LDS-only barrier: does NOT drain vmcnt (in-flight global prefetch survives)
DEVINL void ldsbar() {
    asm volatile("s_waitcnt lgkmcnt(0)\n\ts_barrier" ::: "memory");
    __builtin_amdgcn_sched_barrier(0);
}

// ---------------- prep: weight fragment packing ----------------------------
// B-fragment convention (validated r3-r15): col n = ct*16+(l&15),
// k = kt*32 + ((l>>4)&3)*8 + j.
// bid <256   : et_w [512,128] -> Bf1 [kt16][ct8][lane][j]   (single bf16)
// bid 256-447: wih  [384,128] -> Bf2 [kt4][ct24][lane][j]   (single bf16)
// bid >=448  : heads W1 (3x[256,512]) -> Wf1_hi/lo [h][kt8][ct32][lane][j]
__global__ __launch_bounds__(256) void prep_all(
    const float* __restrict__ et_w, const float* __restrict__ wih,
    const float* __restrict__ w1a, const float* __restrict__ w1b,
    const float* __restrict__ w1c,
    short* __restrict__ Bf1, short* __restrict__ Bf2,
    short* __restrict__ Wf1_hi, short* __restrict__ Wf1_lo)
{
    const int bid = blockIdx.x, t = threadIdx.x;
    if (bid < 256) {
        int idx = bid * 256 + t;            // [0,65536)
        int k = idx >> 7, n = idx & 127;
        float v = et_w[(size_t)k * 128 + n];
        short hi = bf16_rne(v);
        int kt = k >> 5, ct = n >> 4;
        int lane = (((k >> 3) & 3) << 4) | (n & 15);
        int j = k & 7;
        size_t s0 = (((size_t)kt * 8 + ct) * 64 + lane) * 8 + j;
        Bf1[s0] = hi;
    } else if (bid < 448) {
        int idx = (bid - 256) * 256 + t;    // [0,49152)
        int n = idx >> 7, k = idx & 127;
        float v = wih[(size_t)n * 128 + k];
        short hi = bf16_rne(v);
        int kt = k >> 5, ct = n >> 4;
        int lane = (((k >> 3) & 3) << 4) | (n & 15);
        int j = k & 7;
        size_t s0 = (((size_t)kt * 24 + ct) * 64 + lane) * 8 + j;
        Bf2[s0] = hi;
    } else {
        int idx = (bid - 448) * 256 + t;    // [0,393216)
        int h = idx >> 17;
        int r = idx & 131071;
        int k = r >> 9, c = r & 511;
        const float* w1 = (h == 0) ? w1a : (h == 1) ? w1b : w1c;
        float v = w1[(size_t)k * 512 + c];
        short hi = bf16_rne(v), lo = bf16_rne(v - bf16_to_f(hi));
        int kt = k >> 5, ct = c >> 4;
        int lane = (((k >> 3) & 3) << 4) | (c & 15);
        int j = k & 7;
        size_t fidx = ((((size_t)h * 8 + kt) * 32 + ct) * 64 + lane) * 8 + j;
        Wf1_hi[fidx] = hi;
        Wf1_lo[fidx] = lo;
    }
}

// one phase-1 STEP: processes kts 2S,2S+1 from RBUF; stages kts 2S+2,2S+3
// into WBUF; loads A(2S+4,2S+5) into PLD; prefetches next B pair.
// Per-acc MFMA order identical to r14 (kt ascending, hi then lo).
#define PH1_STEP(S, CBE0, CBE1, CBO0, CBO1, NBE0, NBE1, NBO0, NBO1,           \
                 PCV, PLD, RBUF, WBUF)                                        \
    {                                                                         \
        if ((S) < 7) {                                                        \
            const short* bke = Bf1 + (size_t)(2 * (S) + 2) * 4096;            \
            const short* bko = Bf1 + (size_t)(2 * (S) + 3) * 4096;            \
            NBE0 = *(const short8*)(bke + ct0 * 512 + ln8);                   \
            NBE1 = *(const short8*)(bke + ct1 * 512 + ln8);                   \
            NBO0 = *(const short8*)(bko + ct0 * 512 + ln8);                   \
            NBO1 = *(const short8*)(bko + ct1 * 512 + ln8);                   \
            {                                                                 \
                float av[8] = {PCV[0].x, PCV[0].y, PCV[0].z, PCV[0].w,        \
                               PCV[1].x, PCV[1].y, PCV[1].z, PCV[1].w};       \
                short8 h8, l8;                                                \
                cvt_hilo8(av, &h8, &l8);                                      \
                *(short8*)(smem + (WBUF) + aslotb) = h8;                      \
                *(short8*)(smem + (WBUF) + 4096 + aslotb) = l8;               \
            }                                                                 \
            {                                                                 \
                float av[8] = {PCV[2].x, PCV[2].y, PCV[2].z, PCV[2].w,        \
                               PCV[3].x, PCV[3].y, PCV[3].z, PCV[3].w};       \
                short8 h8, l8;                                                \
                cvt_hilo8(av, &h8, &l8);                                      \
                *(short8*)(smem + (WBUF) + 8192 + aslotb) = h8;               \
                *(short8*)(smem + (WBUF) + 12288 + aslotb) = l8;              \
            }                                                                 \
        }                                                                     \
        if ((S) < 6) {                                                        \
            PLD[0] = *(const float4*)(aptr + (size_t)(2 * (S) + 4) * 32);     \
            PLD[1] = *(const float4*)(aptr + (size_t)(2 * (S) + 4) * 32 + 4); \
            PLD[2] = *(const float4*)(aptr + (size_t)(2 * (S) + 5) * 32);     \
            PLD[3] = *(const float4*)(aptr + (size_t)(2 * (S) + 5) * 32 + 4); \
        }                                                                     \
        {                                                                     \
            const char* base = smem + (RBUF);                                 \
            short8 Ahf[4], Alf[4];                                            \
            _Pragma("unroll") for (int rt = 0; rt < 4; ++rt) {                \
                Ahf[rt] = *(const short8*)(base + (rt * 64 + lane) * 16);     \
                Alf[rt] = *(const short8*)(base + 4096 + (rt * 64 + lane) * 16); \
            }                                                                 \
            _Pragma("unroll") for (int rt = 0; rt < 4; ++rt) {                \
                acc1[rt][0] = __builtin_amdgcn_mfma_f32_16x16x32_bf16(Ahf[rt], CBE0, acc1[rt][0], 0, 0, 0); \
                acc1[rt][0] = __builtin_amdgcn_mfma_f32_16x16x32_bf16(Alf[rt], CBE0, acc1[rt][0], 0, 0, 0); \
                acc1[rt][1] = __builtin_amdgcn_mfma_f32_16x16x32_bf16(Ahf[rt], CBE1, acc1[rt][1], 0, 0, 0); \
                acc1[rt][1] = __builtin_amdgcn_mfma_f32_16x16x32_bf16(Alf[rt], CBE1, acc1[rt][1], 0, 0, 0); \
            }                                                                 \
            _Pragma("unroll") for (int rt = 0; rt < 4; ++rt) {                \
                Ahf[rt] = *(const short8*)(base + 8192 + (rt * 64 + lane) * 16); \
                Alf[rt] = *(const short8*)(base + 12288 + (rt * 64 + lane) * 16); \
            }                                                                 \
            _Pragma("unroll") for (int rt = 0; rt < 4; ++rt) {                \
                acc1[rt][0] = __builtin_amdgcn_mfma_f32_16x16x32_bf16(Ahf[rt], CBO0, acc1[rt][0], 0, 0, 0); \
                acc1[rt][0] = __builtin_amdgcn_mfma_f32_16x16x32_bf16(Alf[rt], CBO0, acc1[rt][0], 0, 0, 0); \
                acc1[rt][1] = __builtin_amdgcn_mfma_f32_16x16x32_bf16(Ahf[rt], CBO1, acc1[rt][1], 0, 0, 0); \
                acc1[rt][1] = __builtin_amdgcn_mfma_f32_16x16x32_bf16(Alf[rt], CBO1, acc1[rt][1], 0, 0, 0); \
            }                                                                 \
        }                                                                     \
        ldsbar();                                                             \
    }

// ---------------- fused: ef GEMM -> ef_s -> g GEMM -> gates+pool -----------
// Block = one (b,i) group (64 rows). 256 thr, 4 waves. LDS 35328 B.
//  phase1: A 4 buffers (2 step-bufs x 2 kt x hi/lo 4KB) @0..32768; B in regs
//  phase2: ef_s [64][132] f32 @0 (overlay)
//  phase3: two rt-pair passes; A from ef_s (cvt_pk), B in regs; gates fused
//  epilogue: pool over eh_s @0 + red/s2v/ewv @33792 (shfl reductions)
__global__ __launch_bounds__(256, 3) void fused_kernel(
    const float* __restrict__ x_edge,
    const short* __restrict__ Bf1, const short* __restrict__ Bf2,
    const float* __restrict__ et_b,
    const float* __restrict__ bih, const float* __restrict__ bhh,
    const float* __restrict__ natt_w, const float* __restrict__ eatt_w,
    float* __restrict__ nh_p, float* __restrict__ u_out)
{
    __shared__ __align__(16) char smem[35328];
    const int t = threadIdx.x;
    const int wv = t >> 6, lane = t & 63;
    const int g = blockIdx.x;
    const size_t bm = (size_t)g * 64;

    const int arow = t >> 2, akb = t & 3;
    const int aslotb = (((arow >> 4) * 64) + ((akb << 4) | (arow & 15))) * 16;
    const float* aptr = x_edge + (bm + arow) * 512 + akb * 8;

    const int ct0 = wv * 2, ct1 = wv * 2 + 1;
    const int ln8 = lane * 8;

    f32x4 acc1[4][2] = {};

    float4 paX[4], paY[4];
    short8 bAe0, bAe1, bAo0, bAo1, bBe0, bBe1, bBo0, bBo1;

    // ---- prologue: A(0),A(1) -> cvt -> buf0; paX=A(2,3); B kts 0,1 ----
    {
        float4 t0 = *(const float4*)(aptr);
        float4 t1 = *(const float4*)(aptr + 4);
        float4 t2 = *(const float4*)(aptr + 32);
        float4 t3 = *(const float4*)(aptr + 36);
        paX[0] = *(const float4*)(aptr + 64);
        paX[1] = *(const float4*)(aptr + 68);
        paX[2] = *(const float4*)(aptr + 96);
        paX[3] = *(const float4*)(aptr + 100);
        bAe0 = *(const short8*)(Bf1 + ct0 * 512 + ln8);
        bAe1 = *(const short8*)(Bf1 + ct1 * 512 + ln8);
        bAo0 = *(const short8*)(Bf1 + 4096 + ct0 * 512 + ln8);
        bAo1 = *(const short8*)(Bf1 + 4096 + ct1 * 512 + ln8);
        {
            float av[8] = {t0.x, t0.y, t0.z, t0.w, t1.x, t1.y, t1.z, t1.w};
            short8 h8, l8;
            cvt_hilo8(av, &h8, &l8);
            *(short8*)(smem + aslotb) = h8;
            *(short8*)(smem + 4096 + aslotb) = l8;
        }
        {
            float av[8] = {t2.x, t2.y, t2.z, t2.w, t3.x, t3.y, t3.z, t3.w};
            short8 h8, l8;
            cvt_hilo8(av, &h8, &l8);
            *(short8*)(smem + 8192 + aslotb) = h8;
            *(short8*)(smem + 12288 + aslotb) = l8;
        }
    }
    ldsbar();

    // ---- phase 1: 8 steps (2 kt each), one lgkm-only barrier per step ----
    for (int s = 0; s < 8; s += 2) {
        PH1_STEP(s,     bAe0, bAe1, bAo0, bAo1, bBe0, bBe1, bBo0, bBo1,
                 paX, paY, 0, 16384)
        PH1_STEP(s + 1, bBe0, bBe1, bBo0, bBo1, bAe0, bAe1, bAo0, bAo1,
                 paY, paX, 16384, 0)
    }
    __syncthreads();

    // ---- phase 2: acc1 + et_b -> ef_s [64][132] f32 @0 ----
    float* ef_s = (float*)smem;
#pragma unroll
    for (int c = 0; c < 2; ++c) {
        int col = wv * 32 + c * 16 + (lane & 15);
        float bias = et_b[col];
#pragma unroll
        for (int rt = 0; rt < 4; ++rt) {
#pragma unroll
            for (int q = 0; q < 4; ++q) {
                int row = rt * 16 + ((lane >> 4) << 2) + q;
                ef_s[row * 132 + col] = acc1[rt][c][q] + bias;
            }
        }
    }
    __syncthreads();

    // ---- phase 3 + gates: two rt-pair passes, acc[2][6], B in regs -------
    const int EHP = 132;
    float* eh_s = (float*)smem;
#pragma unroll
    for (int rtp = 0; rtp < 2; ++rtp) {
        f32x4 acch[2][6] = {};
#pragma unroll
        for (int kt = 0; kt < 4; ++kt) {
            const short* bkt = Bf2 + (size_t)kt * 12288;
            short8 Ah[2], Al[2];
#pragma unroll
            for (int r = 0; r < 2; ++r) {
                int rt = rtp * 2 + r;
                const float* src = ef_s + (rt * 16 + (lane & 15)) * 132
                                 + kt * 32 + (lane >> 4) * 8;
                float4 v0 = *(const float4*)(src);
                float4 v1 = *(const float4*)(src + 4);
                float av[8] = {v0.x, v0.y, v0.z, v0.w, v1.x, v1.y, v1.z, v1.w};
                cvt_hilo8(av, &Ah[r], &Al[r]);
            }
#pragma unroll
            for (int c = 0; c < 6; ++c) {
                int ctg = ((c >> 1) << 3) + (wv << 1) + (c & 1);
                short8 Bh = *(const short8*)(bkt + ctg * 512 + ln8);
#pragma unroll
                for (int r = 0; r < 2; ++r) {
                    acch[r][c] = __builtin_amdgcn_mfma_f32_16x16x32_bf16(Ah[r], Bh, acch[r][c], 0, 0, 0);
                    acch[r][c] = __builtin_amdgcn_mfma_f32_16x16x32_bf16(Al[r], Bh, acch[r][c], 0, 0, 0);
                }
            }
        }
        __syncthreads();    // all waves done reading ef_s rows rtp*32..+31
#pragma unroll
        for (int cc = 0; cc < 2; ++cc) {
            int o = (wv << 5) + (cc << 4) + (lane & 15);
            float bco = bih[o] + bhh[o];
            float bcz = bih[128 + o] + bhh[128 + o];
            float bcn = bih[256 + o];
            float bn3 = bhh[256 + o];
#pragma unroll
            for (int r = 0; r < 2; ++r) {
#pragma unroll
                for (int q = 0; q < 4; ++q) {
                    int row = rtp * 32 + r * 16 + ((lane >> 4) << 2) + q;
                    float rr = sigmoidf_(acch[r][cc][q] + bco);
                    float zz = sigmoidf_(acch[r][2 + cc][q] + bcz);
                    float nn = tanhf_(acch[r][4 + cc][q] + bcn + rr * bn3);
                    eh_s[row * EHP + o] = (1.0f - zz) * nn;
                }
            }
        }
    }
    __syncthreads();

    // ---- epilogue: softmax-pool over eh_s (shfl reductions) ----
    float* red  = (float*)(smem + 33792);           // 256 f
    float* s2v  = red + 256;
    float* ewv  = s2v + 64;
    {
        int j = t >> 2, q = t & 3;
        const float* row = eh_s + j * EHP + q * 32;
        const float* wb = natt_w + 128 + q * 32;
        float a = 0.f;
#pragma unroll
        for (int k2 = 0; k2 < 32; ++k2) a = fmaf(row[k2], wb[k2], a);
        red[t] = a;
    }
    __syncthreads();
    if (t < 64) s2v[t] = red[4 * t] + red[4 * t + 1] + red[4 * t + 2] + red[4 * t + 3];
    __syncthreads();
    float sv = s2v[lane];
    float m = sv;
#pragma unroll
    for (int d = 32; d; d >>= 1) m = fmaxf(m, __shfl_xor(m, d, 64));
    float e = __expf(sv - m);
    float ssum = e;
#pragma unroll
    for (int d = 32; d; d >>= 1) ssum += __shfl_xor(ssum, d, 64);
    float inv = 1.0f / ssum;
    if (wv == 0) ewv[lane] = e;
    __syncthreads();
    {
        int o = t & 127, h = t >> 7;
        float a = 0.f;
        for (int j = h * 32; j < h * 32 + 32; ++j)
            a = fmaf(ewv[j], eh_s[j * EHP + o], a);
        __syncthreads();
        red[t] = a;
    }
    __syncthreads();
    if (t < 128) {
        float v = (red[t] + red[t + 128]) * inv;
        nh_p[(size_t)g * 128 + t] = v;
        red[t] = v * eatt_w[t];
    }
    __syncthreads();
    for (int s = 64; s > 0; s >>= 1) {
        if (t < s) red[t] += red[t + s];
        __syncthreads();
    }
    if (t == 0) u_out[g] = red[0];
}

// -------- classifier input --------------------------------------------------
__global__ __launch_bounds__(128) void ci_kernel(
    const float* __restrict__ nh_p, const float* __restrict__ u,
    const int* __restrict__ pairs, float* __restrict__ ci)
{
    const int bp = blockIdx.x;
    const int b  = bp >> 7;
    const int t  = threadIdx.x;
    int i0 = pairs[bp * 2 + 0];
    int i1 = pairs[bp * 2 + 1];
    const float* n0 = nh_p + (size_t)(b * 64 + i0) * 128;
    const float* n1 = nh_p + (size_t)(b * 64 + i1) * 128;
    float s = sigmoidf_(u[b * 64 + i1] - u[b * 64 + i0]);
    float v0 = n0[t], v1 = n1[t];
    ci[(size_t)bp * 256 + t]       = 0.5f * (v0 + v1);
    ci[(size_t)bp * 256 + 128 + t] = s * v1 + (1.0f - s) * v0;
}

// -------- fused head: layer1 MFMA GEMM + ReLU + layer2 (w2 in LDS) ---------
__global__ __launch_bounds__(256, 1) void headcls_kernel(
    const float* __restrict__ ci,
    const short* __restrict__ Wf1_hi, const short* __restrict__ Wf1_lo,
    const float* __restrict__ b1a, const float* __restrict__ b1b,
    const float* __restrict__ b1c,
    const float* __restrict__ w2a, const float* __restrict__ w2b,
    const float* __restrict__ w2c,
    const float* __restrict__ b2a, const float* __restrict__ b2b,
    const float* __restrict__ b2c,
    float* __restrict__ out)
{
    __shared__ __align__(16) char smem[139264];
    const int t = threadIdx.x;
    const int wv = t >> 6, lane = t & 63;
    const int rb = blockIdx.x;
    const int hd = blockIdx.y;
    const float* b1 = hd == 0 ? b1a : hd == 1 ? b1b : b1c;
    const float* w2 = hd == 0 ? w2a : hd == 1 ? w2b : w2c;
    const float* b2 = hd == 0 ? b2a : hd == 1 ? b2b : b2c;
    const int od  = hd == 0 ? 6 : hd == 1 ? 5 : 3;
    const int off = hd == 0 ? 0 : hd == 1 ? 6 : 11;

    const int arow = t >> 2, akb = t & 3;
    const int abyte = ((((arow >> 4) * 64) + ((akb << 4) | (arow & 15))) * 8) * 2;
    const float* aptr = ci + ((size_t)rb * 32 + arow) * 256 + akb * 8;

    f32x4 acc[2][8] = {};

    float4 a0, a1;
    if (t < 128) {
        a0 = *(const float4*)(aptr);
        a1 = *(const float4*)(aptr + 4);
    }
    {
        const char* sh = (const char*)(Wf1_hi + (size_t)hd * 8 * 32 * 512);
        const char* sl = (const char*)(Wf1_lo + (size_t)hd * 8 * 32 * 512);
#pragma unroll
        for (int i = 0; i < 8; ++i) {
            int ch = i * 4 + wv;
            int o2 = ch * 1024 + lane * 16;
            gload_lds16(sh + o2, smem + ch * 1024);
            gload_lds16(sl + o2, smem + 32768 + ch * 1024);
        }
    }
    if (t < 128) {
        float av[8] = {a0.x, a0.y, a0.z, a0.w, a1.x, a1.y, a1.z, a1.w};
        short8 h8, l8;
        cvt_hilo8(av, &h8, &l8);
        *(short8*)(smem + 131072 + abyte) = h8;
        *(short8*)(smem + 131072 + 2048 + abyte) = l8;
    }
    __syncthreads();

    for (int kt = 0; kt < 8; ++kt) {
        const int cur = kt & 1;
        const char* Bh_c = smem + cur * 65536;
        const char* Bl_c = Bh_c + 32768;
        const char* Ah_c = smem + 131072 + cur * 4096;
        const char* Al_c = Ah_c + 2048;

        float4 b0, b1v;
        if (kt < 7) {
            const char* sh = (const char*)(Wf1_hi + ((size_t)hd * 8 + kt + 1) * 32 * 512);
            const char* sl = (const char*)(Wf1_lo + ((size_t)hd * 8 + kt + 1) * 32 * 512);
            char* dBh = smem + (cur ^ 1) * 65536;
#pragma unroll
            for (int i = 0; i < 8; ++i) {
                int ch = i * 4 + wv;
                int o2 = ch * 1024 + lane * 16;
                gload_lds16(sh + o2, dBh + ch * 1024);
                gload_lds16(sl + o2, dBh + 32768 + ch * 1024);
            }
            if (t < 128) {
                b0  = *(const float4*)(aptr + (size_t)(kt + 1) * 32);
                b1v = *(const float4*)(aptr + (size_t)(kt + 1) * 32 + 4);
            }
        }

        short8 Ah[2], Al[2];
#pragma unroll
        for (int rt = 0; rt < 2; ++rt) {
            Ah[rt] = *(const short8*)(Ah_c + (rt * 64 + lane) * 16);
            Al[rt] = *(const short8*)(Al_c + (rt * 64 + lane) * 16);
        }
#pragma unroll
        for (int c = 0; c < 8; ++c) {
            int ctg = wv * 8 + c;
            short8 Bh = *(const short8*)(Bh_c + (ctg * 64 + lane) * 16);
            short8 Bl = *(const short8*)(Bl_c + (ctg * 64 + lane) * 16);
#pragma unroll
            for (int rt = 0; rt < 2; ++rt) {
                acc[rt][c] = __builtin_amdgcn_mfma_f32_16x16x32_bf16(Ah[rt], Bh, acc[rt][c], 0, 0, 0);
                acc[rt][c] = __builtin_amdgcn_mfma_f32_16x16x32_bf16(Al[rt], Bh, acc[rt][c], 0, 0, 0);
                acc[rt][c] = __builtin_amdgcn_mfma_f32_16x16x32_bf16(Ah[rt], Bl, acc[rt][c], 0, 0, 0);
            }
        }

        if (kt < 7 && t < 128) {
            float av[8] = {b0.x, b0.y, b0.z, b0.w, b1v.x, b1v.y, b1v.z, b1v.w};
            short8 h8, l8;
            cvt_hilo8(av, &h8, &l8);
            char* dAh = smem + 131072 + (cur ^ 1) * 4096;
            *(short8*)(dAh + abyte) = h8;
            *(short8*)(dAh + 2048 + abyte) = l8;
        }
        __syncthreads();
    }

    // h_s [32][516] @0 ; w2_s @66048 (both overlay B bufs, post-sync)
    float* h_s  = (float*)smem;
    float* w2_s = (float*)(smem + 66048);
    for (int idx = t; idx < 512 * od; idx += 256) w2_s[idx] = w2[idx];
#pragma unroll
    for (int c = 0; c < 8; ++c) {
        int ctg = wv * 8 + c;
        int col = ctg * 16 + (lane & 15);
        float bias = b1[col];
#pragma unroll
        for (int rt = 0; rt < 2; ++rt) {
#pragma unroll
            for (int q = 0; q < 4; ++q) {
                int row = rt * 16 + ((lane >> 4) << 2) + q;
                h_s[row * 516 + col] = fmaxf(acc[rt][c][q] + bias, 0.f);
            }
        }
    }
    __syncthreads();

    {
        int row = t >> 3, o = t & 7;
        if (o < od) {
            const float* hr = h_s + row * 516;
            float a = b2[o];
            for (int c = 0; c < 512; ++c)
                a = fmaf(hr[c], w2_s[c * od + o], a);
            out[((size_t)rb * 32 + row) * 14 + off + o] = a;
        }
    }
}

// ---------------------------------------------------------------------------
extern "C" void kernel_launch(void* const* d_in, const int* in_sizes, int n_in,
                              void* d_out, int out_size, void* d_ws, size_t ws_size,
                              hipStream_t stream)
{
    const float* x_edge   = (const float*)d_in[1];
    const float* et_w     = (const float*)d_in[6];
    const float* et_b     = (const float*)d_in[7];
    const float* egru_wih = (const float*)d_in[11];
    const float* egru_bih = (const float*)d_in[12];
    const float* egru_bhh = (const float*)d_in[13];
    const float* natt_w   = (const float*)d_in[14];
    const float* eatt_w   = (const float*)d_in[16];
    const float* lr_w1 = (const float*)d_in[18];
    const float* lr_b1 = (const float*)d_in[19];
    const float* lr_w2 = (const float*)d_in[20];
    const float* lr_b2 = (const float*)d_in[21];
    const float* cr_w1 = (const float*)d_in[22];
    const float* cr_b1 = (const float*)d_in[23];
    const float* cr_w2 = (const float*)d_in[24];
    const float* cr_b2 = (const float*)d_in[25];
    const float* mr_w1 = (const float*)d_in[26];
    const float* mr_b1 = (const float*)d_in[27];
    const float* mr_w2 = (const float*)d_in[28];
    const float* mr_b2 = (const float*)d_in[29];
    const int* pairs   = (const int*)d_in[30];
    float* out = (float*)d_out;
    char* ws = (char*)d_ws;

    // workspace layout (bytes) — 4.43 MB total
    short* Bf1    = (short*)(ws + 0);          // 131072 (single plane)
    short* Bf2    = (short*)(ws + 131072);     // 98304  (single plane)
    short* Wf1_hi = (short*)(ws + 229376);     // 786432
    short* Wf1_lo = (short*)(ws + 1015808);    // 786432
    float* nh_p   = (float*)(ws + 1802240);    // 524288
    float* u      = (float*)(ws + 2326528);    // 4096
    float* ci     = (float*)(ws + 2330624);    // 2097152 -> end 4427776

    prep_all<<<1984, 256, 0, stream>>>(et_w, egru_wih, lr_w1, cr_w1, mr_w1,
                                       Bf1, Bf2, Wf1_hi, Wf1_lo);

    fused_kernel<<<1024, 256, 0, stream>>>(
        x_edge, Bf1, Bf2, et_b, egru_bih, egru_bhh, natt_w, eatt_w, nh_p, u);

    ci_kernel<<<2048, 128, 0, stream>>>(nh_p, u, pairs, ci);

    headcls_kernel<<<dim3(64, 3), 256, 0, stream>>>(
        ci, Wf1_hi, Wf1_lo, lr_b1, cr_b1, mr_b1,
        lr_w2, cr_w2, mr_w2, lr_b2, cr_b2, mr_b2, out);
}